// Round 1
// baseline (13186.313 us; speedup 1.0000x reference)
//
#include <hip/hip_runtime.h>
#include <math.h>

#define N_TR 4096
#define N_TE 2048
#define DD   16
#define NB   128
#define NSTEP 32
#define MW   2112   // padded RHS width: 2048 Kstar cols + col2048 = y + zero pad; 33*64

// ---- workspace layout (float offsets) ----
#define OFF_A   0L
#define OFF_B   (OFF_A  + (long)N_TR*N_TR)        // 16777216
#define OFF_LI  (OFF_B  + (long)N_TR*MW)          // + 8650752
#define OFF_XS  (OFF_LI + (long)NSTEP*NB*NB)      // + 524288
#define OFF_TS  (OFF_XS + (long)N_TR*DD)          // + 65536
#define OFF_ACC (OFF_TS + (long)N_TE*DD)          // + 32768
#define WS_FLOATS (OFF_ACC + 2L*N_TE)             // ~26.06M floats ~ 99.4 MB

// ---------------- prep: scale inputs, zero accumulators ----------------
__global__ void k_prep(const float* __restrict__ tr_in, const float* __restrict__ te_in,
                       const float* __restrict__ logl2,
                       float* __restrict__ xs, float* __restrict__ ts, float* __restrict__ acc)
{
    int i = blockIdx.x*256 + threadIdx.x;
    if (i < 2*N_TE) acc[i] = 0.f;
    float sc[DD];
    #pragma unroll
    for (int d=0; d<DD; ++d) sc[d] = rsqrtf(2.f*expf(logl2[d]));
    if (i < N_TR){
        #pragma unroll
        for (int d=0; d<DD; ++d) xs[i*DD+d] = tr_in[i*DD+d]*sc[d];
    } else if (i < N_TR+N_TE){
        int j = i - N_TR;
        #pragma unroll
        for (int d=0; d<DD; ++d) ts[j*DD+d] = te_in[j*DD+d]*sc[d];
    }
}

// ---------------- Knn + sigman2*I (full symmetric) ----------------
__global__ __launch_bounds__(256) void k_knn(const float* __restrict__ xs,
                  const float* __restrict__ lsf2, const float* __restrict__ lsn2,
                  float* __restrict__ A)
{
    __shared__ float sxi[16][17], sxj[16][17];
    int tx = threadIdx.x, ty = threadIdx.y;
    int i = blockIdx.y*16 + ty;
    int j = blockIdx.x*16 + tx;
    sxi[ty][tx] = xs[(blockIdx.y*16+ty)*DD + tx];
    sxj[ty][tx] = xs[(blockIdx.x*16+ty)*DD + tx];
    __syncthreads();
    float d2 = 0.f;
    #pragma unroll
    for (int d=0; d<DD; ++d){ float t = sxi[ty][d]-sxj[tx][d]; d2 += t*t; }
    float v = expf(lsf2[0]) * expf(-d2);
    if (i == j) v += expf(lsn2[0]);
    A[(long)i*N_TR + j] = v;
}

// ---------------- B = [Kstar | y | 0] ----------------
__global__ __launch_bounds__(256) void k_kstar(const float* __restrict__ xs, const float* __restrict__ ts,
                    const float* __restrict__ y, const float* __restrict__ lsf2,
                    float* __restrict__ B)
{
    int tx = threadIdx.x, ty = threadIdx.y;
    int i = blockIdx.y*16 + ty;
    int m = blockIdx.x*16 + tx;
    if (blockIdx.x < N_TE/16){
        __shared__ float sxi[16][17], stj[16][17];
        sxi[ty][tx] = xs[(blockIdx.y*16+ty)*DD + tx];
        stj[ty][tx] = ts[(blockIdx.x*16+ty)*DD + tx];
        __syncthreads();
        float d2 = 0.f;
        #pragma unroll
        for (int d=0; d<DD; ++d){ float t = sxi[ty][d]-stj[tx][d]; d2 += t*t; }
        B[(long)i*MW + m] = expf(lsf2[0]) * expf(-d2);
    } else {
        B[(long)i*MW + m] = (m == N_TE) ? y[i] : 0.f;
    }
}

// ---------------- diag block: factor 128x128 + triangular inverse ----------------
// One workgroup. Maintains only lower triangle of A globally (mirror-load).
__global__ __launch_bounds__(256) void k_chol_diag(float* __restrict__ A, float* __restrict__ Linv, int k)
{
    __shared__ float sA[NB][NB+1];   // working symmetric copy (unscaled cols), later reused for inverse
    __shared__ float sL[NB][NB+1];   // scaled L
    const int tid = threadIdx.x;
    const long base = (long)(k*NB)*N_TR + k*NB;
    for (int idx = tid; idx < NB*NB; idx += 256){
        int r = idx >> 7, c = idx & (NB-1);
        int rr = r > c ? r : c, cc = r > c ? c : r;
        sA[r][c] = A[base + (long)rr*N_TR + cc];
    }
    __syncthreads();
    const int tr = tid >> 4, tc = tid & 15;   // 16x16 threads, each owns 8x8 strided subtile
    for (int j = 0; j < NB; ++j){
        float ajj  = sA[j][j];
        float dinv = 1.0f/ajj;
        float drs  = rsqrtf(ajj);
        // publish scaled column j of L (column j of sA is not written this iteration)
        if (tid < NB) sL[tid][j] = (tid >= j) ? sA[tid][j]*drs : 0.f;
        float cr[8], cl[8];
        #pragma unroll
        for (int u=0;u<8;++u){ cr[u]=sA[tr+16*u][j]; cl[u]=sA[tc+16*u][j]; }
        #pragma unroll
        for (int u=0;u<8;++u){
            int r = tr+16*u;
            if (r > j){
                float f = cr[u]*dinv;
                #pragma unroll
                for (int v=0;v<8;++v){
                    int c = tc+16*v;
                    if (c > j) sA[r][c] -= f*cl[v];
                }
            }
        }
        __syncthreads();
    }
    // triangular inverse: thread c solves L x = e_c, stores x into sA[:, c]
    if (tid < NB){
        const int c = tid;
        for (int i = c; i < NB; ++i){
            float s = (i==c) ? 1.f : 0.f;
            for (int p = c; p < i; ++p) s -= sL[i][p]*sA[p][c];
            sA[i][c] = s / sL[i][i];
        }
    }
    __syncthreads();
    float* Lk = Linv + (long)k*NB*NB;
    for (int idx = tid; idx < NB*NB; idx += 256){
        int r = idx >> 7, c = idx & (NB-1);
        Lk[idx] = (c <= r) ? sA[r][c] : 0.f;           // Linv (lower)
        A[base + (long)r*N_TR + c] = sL[r][c];         // L into diag block (upper zeroed, never read)
    }
}

// ---------------- panel: P = P * Linv^T (in-place, 32 rows x 128 cols per block) ----------------
__global__ __launch_bounds__(256) void k_panel(float* __restrict__ A, const float* __restrict__ Linv, int k)
{
    __shared__ __align__(16) float sP[32][132];
    __shared__ float sI[NB][NB+1];
    const int tid = threadIdx.x;
    const int row0 = (k+1)*NB + blockIdx.x*32;
    const float* Lk = Linv + (long)k*NB*NB;
    for (int idx = tid; idx < NB*NB; idx += 256) sI[idx>>7][idx&127] = Lk[idx];
    #pragma unroll
    for (int l = 0; l < 4; ++l){
        int lin = tid + 256*l;
        int r = lin >> 5, c4 = (lin & 31) << 2;
        *(float4*)&sP[r][c4] = *(const float4*)&A[(long)(row0+r)*N_TR + k*NB + c4];
    }
    __syncthreads();
    const int tr = tid >> 5, tc = tid & 31;
    float acc[4][4];
    #pragma unroll
    for (int u=0;u<4;++u){
        #pragma unroll
        for (int v=0;v<4;++v) acc[u][v]=0.f;
    }
    for (int p = 0; p < NB; ++p){
        float a[4], b[4];
        #pragma unroll
        for (int u=0;u<4;++u) a[u] = sP[tr+8*u][p];
        #pragma unroll
        for (int v=0;v<4;++v) b[v] = sI[tc+32*v][p];
        #pragma unroll
        for (int u=0;u<4;++u){
            #pragma unroll
            for (int v=0;v<4;++v) acc[u][v] += a[u]*b[v];
        }
    }
    #pragma unroll
    for (int u=0;u<4;++u){
        #pragma unroll
        for (int v=0;v<4;++v)
            A[(long)(row0+tr+8*u)*N_TR + k*NB + tc+32*v] = acc[u][v];
    }
}

// ---------------- SYRK trailing update (lower tiles): A -= P P^T ----------------
__global__ __launch_bounds__(256) void k_syrk(float* __restrict__ A, int k)
{
    const int bi = blockIdx.y, bj = blockIdx.x;
    if (bj > bi) return;
    const int tid = threadIdx.x;
    const int row0 = (k+1)*NB + bi*64;
    const int col0 = (k+1)*NB + bj*64;
    __shared__ __align__(16) float sAr[64][20], sAc[64][20];
    const int tr = tid >> 4, tc = tid & 15;
    float acc[4][4];
    #pragma unroll
    for (int u=0;u<4;++u){
        #pragma unroll
        for (int v=0;v<4;++v) acc[u][v]=0.f;
    }
    for (int kk = 0; kk < NB; kk += 16){
        int r = tid >> 2, p4 = (tid & 3) << 2;
        *(float4*)&sAr[r][p4] = *(const float4*)&A[(long)(row0+r)*N_TR + k*NB + kk + p4];
        *(float4*)&sAc[r][p4] = *(const float4*)&A[(long)(col0+r)*N_TR + k*NB + kk + p4];
        __syncthreads();
        #pragma unroll
        for (int p=0;p<16;++p){
            float a[4], b[4];
            #pragma unroll
            for (int u=0;u<4;++u) a[u]=sAr[tr+16*u][p];
            #pragma unroll
            for (int v=0;v<4;++v) b[v]=sAc[tc+16*v][p];
            #pragma unroll
            for (int u=0;u<4;++u){
                #pragma unroll
                for (int v=0;v<4;++v) acc[u][v] += a[u]*b[v];
            }
        }
        __syncthreads();
    }
    #pragma unroll
    for (int u=0;u<4;++u){
        #pragma unroll
        for (int v=0;v<4;++v){
            long off = (long)(row0+tr+16*u)*N_TR + col0+tc+16*v;
            A[off] -= acc[u][v];
        }
    }
}

// ---------------- V_k = Linv_k * B_k (in-place, full 128-row block, 32 cols/block) ----------------
__global__ __launch_bounds__(256) void k_vsolve(float* __restrict__ B, const float* __restrict__ Linv, int k)
{
    __shared__ __align__(16) float sB[NB][36];
    __shared__ float sI[NB][NB+1];
    const int tid = threadIdx.x;
    const int m0 = blockIdx.x*32;
    const float* Lk = Linv + (long)k*NB*NB;
    for (int idx = tid; idx < NB*NB; idx += 256) sI[idx>>7][idx&127] = Lk[idx];
    #pragma unroll
    for (int l = 0; l < 4; ++l){
        int lin = tid + 256*l;
        int p = lin >> 3, mc4 = (lin & 7) << 2;
        *(float4*)&sB[p][mc4] = *(const float4*)&B[(long)(k*NB+p)*MW + m0 + mc4];
    }
    __syncthreads();
    const int tr = tid >> 4, tc = tid & 15;
    float a0[8], a1[8];
    #pragma unroll
    for (int u=0;u<8;++u){ a0[u]=0.f; a1[u]=0.f; }
    for (int p = 0; p < NB; ++p){
        float b0 = sB[p][tc], b1 = sB[p][tc+16];
        #pragma unroll
        for (int u=0;u<8;++u){
            float a = sI[tr+16*u][p];
            a0[u] += a*b0; a1[u] += a*b1;
        }
    }
    #pragma unroll
    for (int u=0;u<8;++u){
        B[(long)(k*NB+tr+16*u)*MW + m0 + tc]      = a0[u];
        B[(long)(k*NB+tr+16*u)*MW + m0 + tc + 16] = a1[u];
    }
}

// ---------------- right-looking TRSM update: B_i -= L_{ik} V_k ----------------
__global__ __launch_bounds__(256) void k_trsm_upd(float* __restrict__ B, const float* __restrict__ A, int k)
{
    const int tid = threadIdx.x;
    const int row0 = (k+1)*NB + blockIdx.y*64;
    const int m0 = blockIdx.x*64;
    __shared__ __align__(16) float sL[64][20];
    __shared__ __align__(16) float sV[16][68];
    const int tr = tid >> 4, tc = tid & 15;
    float acc[4][4];
    #pragma unroll
    for (int u=0;u<4;++u){
        #pragma unroll
        for (int v=0;v<4;++v) acc[u][v]=0.f;
    }
    for (int kk = 0; kk < NB; kk += 16){
        { int r = tid >> 2, p4 = (tid & 3) << 2;
          *(float4*)&sL[r][p4] = *(const float4*)&A[(long)(row0+r)*N_TR + k*NB + kk + p4]; }
        { int p = tid >> 4, mc4 = (tid & 15) << 2;
          *(float4*)&sV[p][mc4] = *(const float4*)&B[(long)(k*NB+kk+p)*MW + m0 + mc4]; }
        __syncthreads();
        #pragma unroll
        for (int p=0;p<16;++p){
            float a[4], b[4];
            #pragma unroll
            for (int u=0;u<4;++u) a[u]=sL[tr+16*u][p];
            #pragma unroll
            for (int v=0;v<4;++v) b[v]=sV[p][tc+16*v];
            #pragma unroll
            for (int u=0;u<4;++u){
                #pragma unroll
                for (int v=0;v<4;++v) acc[u][v] += a[u]*b[v];
            }
        }
        __syncthreads();
    }
    #pragma unroll
    for (int u=0;u<4;++u){
        #pragma unroll
        for (int v=0;v<4;++v)
            B[(long)(row0+tr+16*u)*MW + m0+tc+16*v] -= acc[u][v];
    }
}

// ---------------- reduction: mean[m] = sum V[n][m]*z[n], varsum[m] = sum V^2 ----------------
__global__ __launch_bounds__(256) void k_reduce(const float* __restrict__ B, float* __restrict__ acc)
{
    const int tid = threadIdx.x;
    const long r0 = (long)blockIdx.x*NB;
    float ma[8], va[8];
    #pragma unroll
    for (int u=0;u<8;++u){ ma[u]=0.f; va[u]=0.f; }
    for (int r = 0; r < NB; ++r){
        const float* row = B + (r0 + r)*MW;
        float z = row[N_TE];
        #pragma unroll
        for (int u=0;u<8;++u){
            float v = row[tid + 256*u];
            ma[u] += v*z;
            va[u] += v*v;
        }
    }
    #pragma unroll
    for (int u=0;u<8;++u){
        atomicAdd(&acc[tid+256*u], ma[u]);
        atomicAdd(&acc[N_TE + tid+256*u], va[u]);
    }
}

__global__ void k_final(const float* __restrict__ acc, const float* __restrict__ lsf2,
                        const float* __restrict__ lsn2, float* __restrict__ out)
{
    int m = blockIdx.x*256 + threadIdx.x;
    if (m < N_TE){
        float c = expf(lsf2[0]) + expf(lsn2[0]);
        out[m] = acc[m];
        out[N_TE + m] = c - acc[N_TE + m];
    }
}

extern "C" void kernel_launch(void* const* d_in, const int* in_sizes, int n_in,
                              void* d_out, int out_size, void* d_ws, size_t ws_size,
                              hipStream_t stream)
{
    const float* tr_in = (const float*)d_in[0];
    const float* y     = (const float*)d_in[1];
    const float* te_in = (const float*)d_in[2];
    const float* lsf2  = (const float*)d_in[3];
    const float* logl2 = (const float*)d_in[4];
    const float* lsn2  = (const float*)d_in[5];
    float* ws  = (float*)d_ws;
    float* A   = ws + OFF_A;
    float* B   = ws + OFF_B;
    float* LI  = ws + OFF_LI;
    float* XS  = ws + OFF_XS;
    float* TS  = ws + OFF_TS;
    float* ACC = ws + OFF_ACC;
    float* out = (float*)d_out;

    k_prep<<<(N_TR+N_TE+255)/256, 256, 0, stream>>>(tr_in, te_in, logl2, XS, TS, ACC);
    k_knn<<<dim3(N_TR/16, N_TR/16), dim3(16,16), 0, stream>>>(XS, lsf2, lsn2, A);
    k_kstar<<<dim3(MW/16, N_TR/16), dim3(16,16), 0, stream>>>(XS, TS, y, lsf2, B);

    for (int k = 0; k < NSTEP; ++k){
        k_chol_diag<<<1, 256, 0, stream>>>(A, LI, k);
        int rem = N_TR - (k+1)*NB;
        if (rem > 0){
            k_panel<<<rem/32, 256, 0, stream>>>(A, LI, k);
            k_syrk<<<dim3(rem/64, rem/64), 256, 0, stream>>>(A, k);
        }
    }
    for (int k = 0; k < NSTEP; ++k){
        k_vsolve<<<MW/32, 256, 0, stream>>>(B, LI, k);
        int rem = N_TR - (k+1)*NB;
        if (rem > 0)
            k_trsm_upd<<<dim3(MW/64, rem/64), 256, 0, stream>>>(B, A, k);
    }
    k_reduce<<<NSTEP, 256, 0, stream>>>(B, ACC);
    k_final<<<(N_TE+255)/256, 256, 0, stream>>>(ACC, lsf2, lsn2, out);

    (void)in_sizes; (void)n_in; (void)out_size; (void)ws_size;
}